// Round 3
// baseline (1860.374 us; speedup 1.0000x reference)
//
#include <hip/hip_runtime.h>
#include <hip/hip_bf16.h>

// RowAttention fused kernel. Inputs fp32, OUTPUT fp32, fp32 accumulate (VALU baseline).
// One block per (b,h) row: grid=1024, block=256 (4 waves).
// LDS map (bytes):
//   [0,      65536)  xs   : x[b,:,h,:] as bf16 [256 c][128 w]   (converted at stage-in)
//   [65536,  98304)  qsf  : Q fp32 [64 o][128 w]      (phase 1-2)
//   [98304, 131072)  ksf  : K fp32 [64 o][128 w]      (phase 1-2)
//   [65536, 100352)  attn : bf16 [128 wk][136 wq]     (phase 3+, overlaps dead qsf/ksf)
//   [100352,135168)  vf   : V fp32 [128 v][68 ch]     (per 64-ch chunk)
//   [135168,137216)  red  : float2 [4 oh][64 k0]      (softmax cross-wave reduce)

using u32 = unsigned int;

__device__ __forceinline__ float bflo(u32 u) { union { u32 i; float f; } v; v.i = u << 16; return v.f; }
__device__ __forceinline__ float bfhi(u32 u) { union { u32 i; float f; } v; v.i = u & 0xffff0000u; return v.f; }
__device__ __forceinline__ u32 packbf2(float a, float b) {
    __hip_bfloat16 ha = __float2bfloat16(a);
    __hip_bfloat16 hb = __float2bfloat16(b);
    unsigned short ua, ub;
    __builtin_memcpy(&ua, &ha, 2);
    __builtin_memcpy(&ub, &hb, 2);
    return (u32)ua | ((u32)ub << 16);
}

__global__ __launch_bounds__(256, 1) void rowattn_kernel(
    const float* __restrict__ x,            // (8,256,128,128) fp32
    const float* __restrict__ wq,           // (64,256) fp32
    const float* __restrict__ bq,           // (64,)
    const float* __restrict__ wk,           // (64,256)
    const float* __restrict__ bk,           // (64,)
    const float* __restrict__ wv,           // (256,256)
    const float* __restrict__ bv,           // (256,)
    const float* __restrict__ gamma,        // (1,)
    float* __restrict__ out)                // (8,256,128,128) fp32
{
    __shared__ __align__(16) char smem[137216];

    const int t  = threadIdx.x;
    const int bh = blockIdx.x;
    const int b  = bh >> 7;
    const int h  = bh & 127;
    const int k0 = t & 63;
    const int oh = t >> 6;                                   // wave id
    const int ohs = __builtin_amdgcn_readfirstlane(oh);      // force wave-uniform for s_load
    const int w0 = k0 * 2;                                   // this thread's w pair

    u32*   xs32   = (u32*)smem;
    float* qsf    = (float*)(smem + 65536);
    float* ksf    = (float*)(smem + 98304);
    u32*   attn32 = (u32*)(smem + 65536);
    float* vf     = (float*)(smem + 100352);
    float2* red   = (float2*)(smem + 135168);

    // ---------------- P0: stage x[b,:,h,:] into LDS as bf16 pairs -----------------
    {
        const float4* xg = (const float4*)x;                 // 4 fp32 per vec
        const int base = b * 1048576 + h * 32;               // float4 units
#pragma unroll
        for (int i = 0; i < 32; ++i) {
            int idx = t + i * 256;                           // 0..8191
            int c   = idx >> 5;                              // 32 float4 per (c) row
            int f   = idx & 31;
            float4 v = xg[base + c * 4096 + f];
            uint2 p;
            p.x = packbf2(v.x, v.y);
            p.y = packbf2(v.z, v.w);
            *(uint2*)&xs32[c * 64 + f * 2] = p;
        }
    }
    __syncthreads();

    // ---------------- P1: Q,K projections -> qsf/ksf fp32 -------------------------
    // thread computes Q/K[o = ohs*16+i][w0, w0+1]
    {
        float accq[16][2], acck[16][2];
#pragma unroll
        for (int i = 0; i < 16; ++i) {
            float bqv = bq[ohs * 16 + i];
            float bkv = bk[ohs * 16 + i];
            accq[i][0] = bqv; accq[i][1] = bqv;
            acck[i][0] = bkv; acck[i][1] = bkv;
        }
#pragma unroll 2
        for (int cc = 0; cc < 256; cc += 2) {
            u32 xp0 = xs32[cc * 64 + k0];                    // xs[cc][w0..w0+1]
            u32 xp1 = xs32[cc * 64 + 64 + k0];               // xs[cc+1][w0..w0+1]
            float x00 = bflo(xp0), x01 = bfhi(xp0);
            float x10 = bflo(xp1), x11 = bfhi(xp1);
#pragma unroll
            for (int i = 0; i < 16; ++i) {
                float2 wqp = *(const float2*)&wq[(ohs * 16 + i) * 256 + cc];  // uniform -> s_load
                float2 wkp = *(const float2*)&wk[(ohs * 16 + i) * 256 + cc];
                accq[i][0] += wqp.x * x00; accq[i][0] += wqp.y * x10;
                accq[i][1] += wqp.x * x01; accq[i][1] += wqp.y * x11;
                acck[i][0] += wkp.x * x00; acck[i][0] += wkp.y * x10;
                acck[i][1] += wkp.x * x01; acck[i][1] += wkp.y * x11;
            }
        }
#pragma unroll
        for (int i = 0; i < 16; ++i) {
            int o = ohs * 16 + i;
            *(float2*)&qsf[o * 128 + w0] = make_float2(accq[i][0], accq[i][1]);
            *(float2*)&ksf[o * 128 + w0] = make_float2(acck[i][0], acck[i][1]);
        }
    }
    __syncthreads();

    // ---------------- P2: S[wq][wk] = sum_o Q[o][wq] K[o][wk] ---------------------
    // thread owns wq in {w0, w0+1}, wk in {ohs*32 + j}
    float accs[32][2];
    {
#pragma unroll
        for (int j = 0; j < 32; ++j) { accs[j][0] = 0.f; accs[j][1] = 0.f; }
#pragma unroll 2
        for (int o = 0; o < 64; ++o) {
            float2 qp = *(const float2*)&qsf[o * 128 + w0];  // per-lane b64
            const float* kk = &ksf[o * 128 + ohs * 32];      // uniform broadcast
#pragma unroll
            for (int j = 0; j < 32; ++j) {
                float kv = kk[j];
                accs[j][0] += qp.x * kv;
                accs[j][1] += qp.y * kv;
            }
        }
    }

    // ---------------- P3: softmax over wk, write attn[wk][wq] bf16 ----------------
    {
        float m0 = -1e30f, m1 = -1e30f;
#pragma unroll
        for (int j = 0; j < 32; ++j) { m0 = fmaxf(m0, accs[j][0]); m1 = fmaxf(m1, accs[j][1]); }
        red[oh * 64 + k0] = make_float2(m0, m1);
        __syncthreads();                                     // also orders P2 reads before attn writes
        m0 = -1e30f; m1 = -1e30f;
#pragma unroll
        for (int o2 = 0; o2 < 4; ++o2) {
            float2 r = red[o2 * 64 + k0];
            m0 = fmaxf(m0, r.x); m1 = fmaxf(m1, r.y);
        }
        __syncthreads();                                     // red reads done before reuse
        float s0 = 0.f, s1 = 0.f;
#pragma unroll
        for (int j = 0; j < 32; ++j) {
            float e0 = __expf(accs[j][0] - m0);
            float e1 = __expf(accs[j][1] - m1);
            accs[j][0] = e0; accs[j][1] = e1;
            s0 += e0; s1 += e1;
        }
        red[oh * 64 + k0] = make_float2(s0, s1);
        __syncthreads();
        s0 = 0.f; s1 = 0.f;
#pragma unroll
        for (int o2 = 0; o2 < 4; ++o2) {
            float2 r = red[o2 * 64 + k0];
            s0 += r.x; s1 += r.y;
        }
        float inv0 = 1.0f / s0, inv1 = 1.0f / s1;
        // attn[wk = ohs*32+j][wq pair at w0]  (conflict-free: word = 68*wk + k0)
#pragma unroll
        for (int j = 0; j < 32; ++j) {
            attn32[(ohs * 32 + j) * 68 + k0] = packbf2(accs[j][0] * inv0, accs[j][1] * inv1);
        }
    }
    __syncthreads();

    // ---------------- P4: per 64-channel chunk: V then O = V A^T + epilogue -------
    const float g = gamma[0];
    const int chl_base = ohs * 16;
    for (int q = 0; q < 4; ++q) {
        // P4a: V[ch][v] for ch = q*64 + chl_base + i, v in {w0, w0+1}
        {
            float accv[16][2];
#pragma unroll
            for (int i = 0; i < 16; ++i) {
                float bvv = bv[q * 64 + chl_base + i];
                accv[i][0] = bvv; accv[i][1] = bvv;
            }
#pragma unroll 2
            for (int cc = 0; cc < 256; cc += 2) {
                u32 xp0 = xs32[cc * 64 + k0];
                u32 xp1 = xs32[cc * 64 + 64 + k0];
                float x00 = bflo(xp0), x01 = bfhi(xp0);
                float x10 = bflo(xp1), x11 = bfhi(xp1);
#pragma unroll
                for (int i = 0; i < 16; ++i) {
                    float2 wvp = *(const float2*)&wv[(q * 64 + chl_base + i) * 256 + cc];
                    accv[i][0] += wvp.x * x00; accv[i][0] += wvp.y * x10;
                    accv[i][1] += wvp.x * x01; accv[i][1] += wvp.y * x11;
                }
            }
#pragma unroll
            for (int i = 0; i < 16; ++i) {
                vf[w0 * 68 + chl_base + i]       = accv[i][0];
                vf[(w0 + 1) * 68 + chl_base + i] = accv[i][1];
            }
        }
        __syncthreads();
        // P4b: O[ch][w] = sum_v V[ch][v] * attn[w][v];  out = g*O + x  (fp32 stores)
        {
            float acco[16][2];
#pragma unroll
            for (int i = 0; i < 16; ++i) { acco[i][0] = 0.f; acco[i][1] = 0.f; }
#pragma unroll 2
            for (int v = 0; v < 128; ++v) {
                u32 ap = attn32[v * 68 + k0];                // attn[v][w0..w0+1], conflict-free
                float a0 = bflo(ap), a1 = bfhi(ap);
                const float* vv = &vf[v * 68 + chl_base];    // uniform broadcast
#pragma unroll
                for (int i = 0; i < 16; ++i) {
                    float vvv = vv[i];
                    acco[i][0] += vvv * a0;
                    acco[i][1] += vvv * a1;
                }
            }
#pragma unroll
            for (int i = 0; i < 16; ++i) {
                int ch = q * 64 + chl_base + i;
                u32 xp = xs32[ch * 64 + k0];                 // residual from bf16-staged x
                float o0 = g * acco[i][0] + bflo(xp);
                float o1 = g * acco[i][1] + bfhi(xp);
                int oidx = ((b * 256 + ch) * 128 + h) * 128 + w0;   // fp32 units
                *(float2*)&out[oidx] = make_float2(o0, o1);  // coalesced 8B stores
            }
        }
        __syncthreads();
    }
}

extern "C" void kernel_launch(void* const* d_in, const int* in_sizes, int n_in,
                              void* d_out, int out_size, void* d_ws, size_t ws_size,
                              hipStream_t stream) {
    const float* x     = (const float*)d_in[0];
    const float* wq    = (const float*)d_in[1];
    const float* bq    = (const float*)d_in[2];
    const float* wk    = (const float*)d_in[3];
    const float* bk    = (const float*)d_in[4];
    const float* wv    = (const float*)d_in[5];
    const float* bv    = (const float*)d_in[6];
    const float* gamma = (const float*)d_in[7];
    float* out = (float*)d_out;

    dim3 grid(1024), block(256);
    hipLaunchKernelGGL(rowattn_kernel, grid, block, 0, stream,
                       x, wq, bq, wk, bk, wv, bv, gamma, out);
}

// Round 4
// 346.988 us; speedup vs baseline: 5.3615x; 5.3615x over previous
//
#include <hip/hip_runtime.h>
#include <hip/hip_bf16.h>

// RowAttention, MFMA version (bf16 MFMA, fp32 acc). Inputs fp32, output fp32.
// One block per (b,h) row: grid=1024, block=512 (8 waves), 1 block/CU (LDS 138.5 KB).
//
// GEMMs (all v_mfma_f32_16x16x32_bf16, verified layouts m89/m91/m120):
//   P1: Q[o][w]  = Wq·X + bq   (M=64,N=128,K=256)   A=Wq rows, B=X via Xt[w][c]
//       K[o][w]  = Wk·X + bk
//   P2: St[wk][wq] = K^T-style: sum_o K[o][wk]·Q[o][wq]  (M=128,N=128,K=64)
//       A=Kt[wk][o], B=Qt[wq][o]   -> softmax over wk = C-layout ROW reduce (xor16/32)
//   P3: P[wq][wk] = softmax -> Pl[wq][wk] bf16 (exactly the PV B-operand layout)
//   P4: V[c][v] = Wv·X + bv (per 64-c chunk); O[c][w] = sum_v V[c][v]·Pl[w][v]
//       epilogue out = g*O + x  (residual from bf16 Xt)
//
// All LDS row strides are ==8 mod 16 bf16 (words==4 mod 8): 16B-aligned ds_read_b128
// frag loads with uniform 8 words/bank -> conflict-free.
// LDS map (bytes):
//   [0,     67584)  Xt  [128 w][264 c] bf16
//   [67584, 86016)  Qt  [128 wq][72 o] bf16      | Pl [128 wq][136 wk] bf16 overlays
//   [86016,104448)  Kt  [128 wk][72 o] bf16      |   Qt+Kt after P2 (ends 102400)
//   [104448,122880) wbuf: P0 fp32 scratch [16][136] / P1 wq_c+wk_c [64][72]x2 / P4 wv_c
//   [122880,140288) Vl  [64 c][136 v] bf16
//   [140288,141824) biases fp32: bq[64] bk[64] bv[256]

typedef short bf16x8 __attribute__((ext_vector_type(8)));
typedef float f32x4 __attribute__((ext_vector_type(4)));
using u32 = unsigned int;
using u16 = unsigned short;

#define XT_OFF   0
#define XT_SB    528
#define QT_OFF   67584
#define KT_OFF   86016
#define QK_SB    144
#define PL_OFF   67584
#define PL_SB    272
#define WQC_OFF  104448
#define WKC_OFF  113664
#define WC_SB    144
#define SC_OFF   104448
#define VL_OFF   122880
#define VL_SB    272
#define BIAS_OFF 140288
#define LDS_TOTAL 141824

__device__ __forceinline__ u16 bfbits(float f) {
    __hip_bfloat16 h = __float2bfloat16(f);
    u16 u; __builtin_memcpy(&u, &h, 2); return u;
}
__device__ __forceinline__ u32 packbf2(float a, float b) {
    return (u32)bfbits(a) | ((u32)bfbits(b) << 16);
}
__device__ __forceinline__ float bf2f(u16 u) {
    union { u32 i; float f; } v; v.i = ((u32)u) << 16; return v.f;
}

__global__ __launch_bounds__(512, 1) void rowattn_mfma(
    const float* __restrict__ x,      // (8,256,128,128)
    const float* __restrict__ wq,     // (64,256)
    const float* __restrict__ bq,     // (64,)
    const float* __restrict__ wk,     // (64,256)
    const float* __restrict__ bk,     // (64,)
    const float* __restrict__ wv,     // (256,256)
    const float* __restrict__ bv,     // (256,)
    const float* __restrict__ gamma,  // (1,)
    float* __restrict__ out)          // (8,256,128,128)
{
    __shared__ __align__(16) char smem[LDS_TOTAL];
    const int t  = threadIdx.x;
    const int bh = blockIdx.x;
    const int b  = bh >> 7;
    const int h  = bh & 127;
    const int l  = t & 63;
    const int a  = l & 15;                                  // MFMA col-within-tile
    const int q  = l >> 4;                                  // MFMA quad
    const int nw = __builtin_amdgcn_readfirstlane(t >> 6);  // wave id 0..7 = n-strip

    float* biasl = (float*)(smem + BIAS_OFF);
    if (t < 384) {
        float v;
        if (t < 64) v = bq[t];
        else if (t < 128) v = bk[t - 64];
        else v = bv[t - 128];
        biasl[t] = v;
    }

    // ---- P0: stage x[b,:,h,:] transposed -> Xt[w][c] bf16, via fp32 scratch tile ----
    {
        float* sc = (float*)(smem + SC_OFF);                // [16 c][136 w] fp32
        const int cl  = t >> 5;                             // 0..15
        const int w4  = (t & 31) * 4;
        const int wrd = t >> 2;                             // 0..127
        const int c4  = (t & 3) * 4;
#pragma unroll 1
        for (int p = 0; p < 16; ++p) {
            float4 v = *(const float4*)&x[((b * 256 + p * 16 + cl) * 128 + h) * 128 + w4];
            __syncthreads();                                // prev pass scratch reads done (also bias)
            *(float4*)&sc[cl * 136 + w4] = v;
            __syncthreads();                                // scratch ready
            float s0 = sc[(c4 + 0) * 136 + wrd];
            float s1 = sc[(c4 + 1) * 136 + wrd];
            float s2 = sc[(c4 + 2) * 136 + wrd];
            float s3 = sc[(c4 + 3) * 136 + wrd];
            uint2 pk; pk.x = packbf2(s0, s1); pk.y = packbf2(s2, s3);
            *(uint2*)(smem + XT_OFF + wrd * XT_SB + (p * 16 + c4) * 2) = pk;
        }
    }

    // ---- P1: Q,K projections -> Qt[wq][o], Kt[wk][o] bf16 ----
    {
        f32x4 accQ[4], accK[4];
#pragma unroll
        for (int mt = 0; mt < 4; ++mt) {
            f32x4 cq, ck;
#pragma unroll
            for (int r = 0; r < 4; ++r) {
                cq[r] = biasl[mt * 16 + q * 4 + r];
                ck[r] = biasl[64 + mt * 16 + q * 4 + r];
            }
            accQ[mt] = cq; accK[mt] = ck;
        }
        const int row = t >> 3;                             // 0..63
        const int k8  = (t & 7) * 8;
#pragma unroll 1
        for (int kc = 0; kc < 4; ++kc) {
            {   // stage weight chunks (64 rows x 64 k) as bf16
                const float* s = &wq[row * 256 + kc * 64 + k8];
                float4 u0 = *(const float4*)s, v0 = *(const float4*)(s + 4);
                uint4 p0; p0.x = packbf2(u0.x, u0.y); p0.y = packbf2(u0.z, u0.w);
                p0.z = packbf2(v0.x, v0.y); p0.w = packbf2(v0.z, v0.w);
                *(uint4*)(smem + WQC_OFF + row * WC_SB + k8 * 2) = p0;
                const float* s2 = &wk[row * 256 + kc * 64 + k8];
                float4 u1 = *(const float4*)s2, v1 = *(const float4*)(s2 + 4);
                uint4 p1; p1.x = packbf2(u1.x, u1.y); p1.y = packbf2(u1.z, u1.w);
                p1.z = packbf2(v1.x, v1.y); p1.w = packbf2(v1.z, v1.w);
                *(uint4*)(smem + WKC_OFF + row * WC_SB + k8 * 2) = p1;
            }
            __syncthreads();
#pragma unroll
            for (int ks = 0; ks < 2; ++ks) {
                bf16x8 bx = *(const bf16x8*)(smem + XT_OFF + (nw * 16 + a) * XT_SB + (kc * 64 + ks * 32) * 2 + q * 16);
#pragma unroll
                for (int mt = 0; mt < 4; ++mt) {
                    bf16x8 aq = *(const bf16x8*)(smem + WQC_OFF + (mt * 16 + a) * WC_SB + ks * 64 + q * 16);
                    accQ[mt] = __builtin_amdgcn_mfma_f32_16x16x32_bf16(aq, bx, accQ[mt], 0, 0, 0);
                    bf16x8 ak = *(const bf16x8*)(smem + WKC_OFF + (mt * 16 + a) * WC_SB + ks * 64 + q * 16);
                    accK[mt] = __builtin_amdgcn_mfma_f32_16x16x32_bf16(ak, bx, accK[mt], 0, 0, 0);
                }
            }
            __syncthreads();
        }
        // write Qt/Kt transposed: C[m=o][n=w] -> Qt[w][o] (4 consecutive o per lane = b64)
#pragma unroll
        for (int mt = 0; mt < 4; ++mt) {
            uint2 pq; pq.x = packbf2(accQ[mt][0], accQ[mt][1]); pq.y = packbf2(accQ[mt][2], accQ[mt][3]);
            *(uint2*)(smem + QT_OFF + (nw * 16 + a) * QK_SB + (mt * 16 + q * 4) * 2) = pq;
            uint2 pk; pk.x = packbf2(accK[mt][0], accK[mt][1]); pk.y = packbf2(accK[mt][2], accK[mt][3]);
            *(uint2*)(smem + KT_OFF + (nw * 16 + a) * QK_SB + (mt * 16 + q * 4) * 2) = pk;
        }
    }
    __syncthreads();

    // ---- P2: St[wk][wq], wave owns wq-strip nw ----
    f32x4 st[8];
#pragma unroll
    for (int mt = 0; mt < 8; ++mt) st[mt] = (f32x4){0.f, 0.f, 0.f, 0.f};
#pragma unroll
    for (int ks = 0; ks < 2; ++ks) {
        bf16x8 bqf = *(const bf16x8*)(smem + QT_OFF + (nw * 16 + a) * QK_SB + ks * 64 + q * 16);
#pragma unroll
        for (int mt = 0; mt < 8; ++mt) {
            bf16x8 akf = *(const bf16x8*)(smem + KT_OFF + (mt * 16 + a) * QK_SB + ks * 64 + q * 16);
            st[mt] = __builtin_amdgcn_mfma_f32_16x16x32_bf16(akf, bqf, st[mt], 0, 0, 0);
        }
    }
    // ---- P3: softmax over wk (C-layout rows: in-lane + quad shuffles) ----
    {
        float mx = -3.0e38f;
#pragma unroll
        for (int mt = 0; mt < 8; ++mt)
#pragma unroll
            for (int r = 0; r < 4; ++r) mx = fmaxf(mx, st[mt][r]);
        mx = fmaxf(mx, __shfl_xor(mx, 16, 64));
        mx = fmaxf(mx, __shfl_xor(mx, 32, 64));
        float sum = 0.f;
#pragma unroll
        for (int mt = 0; mt < 8; ++mt)
#pragma unroll
            for (int r = 0; r < 4; ++r) { float e = __expf(st[mt][r] - mx); st[mt][r] = e; sum += e; }
        sum += __shfl_xor(sum, 16, 64);
        sum += __shfl_xor(sum, 32, 64);
        float inv = 1.0f / sum;
        __syncthreads();                                    // Qt/Kt frag reads done before Pl overlay
#pragma unroll
        for (int mt = 0; mt < 8; ++mt) {
            uint2 pp; pp.x = packbf2(st[mt][0] * inv, st[mt][1] * inv);
            pp.y = packbf2(st[mt][2] * inv, st[mt][3] * inv);
            *(uint2*)(smem + PL_OFF + (nw * 16 + a) * PL_SB + (mt * 16 + q * 4) * 2) = pp;
        }
        __syncthreads();
    }

    // ---- P4: per 64-channel chunk: V = Wv·X + bv; O = V·P^T; out = g*O + x ----
    const float g = gamma[0];
    const int row = t >> 3;
    const int k8  = (t & 7) * 8;
#pragma unroll 1
    for (int mc = 0; mc < 4; ++mc) {
        f32x4 accV[4];
#pragma unroll
        for (int mt = 0; mt < 4; ++mt) {
            f32x4 cv;
#pragma unroll
            for (int r = 0; r < 4; ++r) cv[r] = biasl[128 + mc * 64 + mt * 16 + q * 4 + r];
            accV[mt] = cv;
        }
#pragma unroll 1
        for (int kc = 0; kc < 4; ++kc) {
            const float* s = &wv[(mc * 64 + row) * 256 + kc * 64 + k8];
            float4 u0 = *(const float4*)s, v0 = *(const float4*)(s + 4);
            uint4 p0; p0.x = packbf2(u0.x, u0.y); p0.y = packbf2(u0.z, u0.w);
            p0.z = packbf2(v0.x, v0.y); p0.w = packbf2(v0.z, v0.w);
            *(uint4*)(smem + WQC_OFF + row * WC_SB + k8 * 2) = p0;
            __syncthreads();
#pragma unroll
            for (int ks = 0; ks < 2; ++ks) {
                bf16x8 bx = *(const bf16x8*)(smem + XT_OFF + (nw * 16 + a) * XT_SB + (kc * 64 + ks * 32) * 2 + q * 16);
#pragma unroll
                for (int mt = 0; mt < 4; ++mt) {
                    bf16x8 av = *(const bf16x8*)(smem + WQC_OFF + (mt * 16 + a) * WC_SB + ks * 64 + q * 16);
                    accV[mt] = __builtin_amdgcn_mfma_f32_16x16x32_bf16(av, bx, accV[mt], 0, 0, 0);
                }
            }
            __syncthreads();
        }
        // write Vl[c][v]: scattered u16 (4 rows per lane), ~2 words/bank
#pragma unroll
        for (int mt = 0; mt < 4; ++mt)
#pragma unroll
            for (int r = 0; r < 4; ++r)
                *(u16*)(smem + VL_OFF + (mt * 16 + q * 4 + r) * VL_SB + (nw * 16 + a) * 2) = bfbits(accV[mt][r]);
        __syncthreads();
        // O-GEMM: A=Vl[c][v], B=Pl[w][v]
        f32x4 accO[4];
#pragma unroll
        for (int mt = 0; mt < 4; ++mt) accO[mt] = (f32x4){0.f, 0.f, 0.f, 0.f};
#pragma unroll
        for (int ks = 0; ks < 4; ++ks) {
            bf16x8 bp = *(const bf16x8*)(smem + PL_OFF + (nw * 16 + a) * PL_SB + ks * 64 + q * 16);
#pragma unroll
            for (int mt = 0; mt < 4; ++mt) {
                bf16x8 av = *(const bf16x8*)(smem + VL_OFF + (mt * 16 + a) * VL_SB + ks * 64 + q * 16);
                accO[mt] = __builtin_amdgcn_mfma_f32_16x16x32_bf16(av, bp, accO[mt], 0, 0, 0);
            }
        }
        // epilogue: out = g*O + x (residual from bf16 Xt)
#pragma unroll
        for (int mt = 0; mt < 4; ++mt) {
#pragma unroll
            for (int r = 0; r < 4; ++r) {
                int c = mc * 64 + mt * 16 + q * 4 + r;
                int w = nw * 16 + a;
                u16 xv = *(const u16*)(smem + XT_OFF + w * XT_SB + c * 2);
                out[((b * 256 + c) * 128 + h) * 128 + w] = g * accO[mt][r] + bf2f(xv);
            }
        }
        __syncthreads();                                    // Vl/wv_c reuse next mc
    }
}

extern "C" void kernel_launch(void* const* d_in, const int* in_sizes, int n_in,
                              void* d_out, int out_size, void* d_ws, size_t ws_size,
                              hipStream_t stream) {
    const float* x     = (const float*)d_in[0];
    const float* wq    = (const float*)d_in[1];
    const float* bq    = (const float*)d_in[2];
    const float* wk    = (const float*)d_in[3];
    const float* bk    = (const float*)d_in[4];
    const float* wv    = (const float*)d_in[5];
    const float* bv    = (const float*)d_in[6];
    const float* gamma = (const float*)d_in[7];
    float* out = (float*)d_out;

    dim3 grid(1024), block(512);
    hipLaunchKernelGGL(rowattn_mfma, grid, block, 0, stream,
                       x, wq, bq, wk, bk, wv, bv, gamma, out);
}